// Round 1
// baseline (419.934 us; speedup 1.0000x reference)
//
#include <hip/hip_runtime.h>

// ---- problem dims (hardcoded) ----
#define BATCH 8
#define SEQ   2048
#define DM    512
#define DK    64
#define NROW  (BATCH*SEQ)          // 16384 total rows
#define EPSV  1e-6f

typedef _Float16 f16x8 __attribute__((ext_vector_type(8)));
typedef _Float16 f16x4 __attribute__((ext_vector_type(4)));
typedef _Float16 f16x2 __attribute__((ext_vector_type(2)));
typedef float    f32x4 __attribute__((ext_vector_type(4)));

// ===================== K0: convert W to fp16 =====================
__global__ void wcvt(const float* __restrict__ wq, const float* __restrict__ wk,
                     const float* __restrict__ wv, _Float16* __restrict__ w16) {
    int idx = (blockIdx.x * 256 + threadIdx.x) * 4;   // grid 96 -> 98304 elems
    int z = idx >> 15;                                 // 32768 per matrix
    int off = idx & 32767;
    const float* src = (z == 0) ? wq : ((z == 1) ? wk : wv);
    float4 g = *reinterpret_cast<const float4*>(src + off);
    f16x4 h = { (_Float16)g.x, (_Float16)g.y, (_Float16)g.z, (_Float16)g.w };
    *reinterpret_cast<f16x4*>(w16 + idx) = h;
}

// ===================== K1: QKV projection (MFMA f16) =====================
// out[row][d] = sum_m in[row][m] * W[d][m] + b[d]
// z=0: q16[row][64], z=1: k16[row][64], z=2: vT16[b][d][s] (transposed)
__global__ __launch_bounds__(256) void proj(
    const float* __restrict__ query, const float* __restrict__ key,
    const float* __restrict__ value, const _Float16* __restrict__ w16,
    const float* __restrict__ bq, const float* __restrict__ bk, const float* __restrict__ bv,
    _Float16* __restrict__ q16, _Float16* __restrict__ k16, _Float16* __restrict__ vT16)
{
    __shared__ _Float16 xsh[64][72];   // pitch 72: 16B-aligned rows, conflict-padded

    const int t = threadIdx.x;
    const int wave = t >> 6, lane = t & 63;
    const int n16 = lane & 15, quad = lane >> 4;
    const int z = blockIdx.y;
    const float* in   = (z == 0) ? query : ((z == 1) ? key : value);
    const float* bias = (z == 0) ? bq    : ((z == 1) ? bk  : bv);
    const _Float16* wz = w16 + z * (DK * DM);
    const int row0 = blockIdx.x * 64;

    f32x4 acc[4] = {};   // 4 n-tiles of 16 cols each

    for (int kk = 0; kk < DM; kk += 64) {
        // stage input tile 64x64 fp32 -> fp16 LDS (coalesced float4 reads)
        #pragma unroll
        for (int it = 0; it < 4; ++it) {
            int f = t + it * 256;              // 0..1023 float4 slots
            int row = f >> 4, kq = f & 15;
            float4 g = *reinterpret_cast<const float4*>(in + (size_t)(row0 + row) * DM + kk + kq * 4);
            f16x4 h = { (_Float16)g.x, (_Float16)g.y, (_Float16)g.z, (_Float16)g.w };
            *reinterpret_cast<f16x4*>(&xsh[row][kq * 4]) = h;
        }
        __syncthreads();
        // A-frags for this wave's 16-row slice
        f16x8 a0 = *reinterpret_cast<const f16x8*>(&xsh[wave * 16 + n16][quad * 8]);
        f16x8 a1 = *reinterpret_cast<const f16x8*>(&xsh[wave * 16 + n16][32 + quad * 8]);
        #pragma unroll
        for (int nt = 0; nt < 4; ++nt) {
            const _Float16* bbase = wz + (size_t)(nt * 16 + n16) * DM + kk + quad * 8;
            f16x8 b0 = *reinterpret_cast<const f16x8*>(bbase);
            f16x8 b1 = *reinterpret_cast<const f16x8*>(bbase + 32);
            acc[nt] = __builtin_amdgcn_mfma_f32_16x16x32_f16(a0, b0, acc[nt], 0, 0, 0);
            acc[nt] = __builtin_amdgcn_mfma_f32_16x16x32_f16(a1, b1, acc[nt], 0, 0, 0);
        }
        __syncthreads();
    }

    const int batch = row0 >> 11, row0s = row0 & (SEQ - 1);
    if (z < 2) {
        _Float16* out = (z == 0) ? q16 : k16;
        #pragma unroll
        for (int nt = 0; nt < 4; ++nt) {
            float bzv = bias[nt * 16 + n16];
            #pragma unroll
            for (int r = 0; r < 4; ++r) {
                int grow = row0 + wave * 16 + quad * 4 + r;   // C layout: row=quad*4+reg
                out[(size_t)grow * DK + nt * 16 + n16] = (_Float16)(acc[nt][r] + bzv);
            }
        }
    } else {
        // v transposed: vT[batch][d][s], 4 consecutive s pack into one 8B store
        #pragma unroll
        for (int nt = 0; nt < 4; ++nt) {
            float bzv = bias[nt * 16 + n16];
            f16x4 h = { (_Float16)(acc[nt][0] + bzv), (_Float16)(acc[nt][1] + bzv),
                        (_Float16)(acc[nt][2] + bzv), (_Float16)(acc[nt][3] + bzv) };
            int d = nt * 16 + n16;
            int sbase = row0s + wave * 16 + quad * 4;
            *reinterpret_cast<f16x4*>(vT16 + ((size_t)(batch * DK + d)) * SEQ + sbase) = h;
        }
    }
}

// ===================== K2: fused attention =====================
// 8 query rows per block; full-row scores in LDS; 2 blocks/CU.
#define RTILE 8
#define SCP   2064   // sc pitch (floats): padded, 16B-aligned (2064*4 % 16 == 0)

__global__ __launch_bounds__(256, 2) void attn(
    const _Float16* __restrict__ q16,   // [16384][64]
    const _Float16* __restrict__ k16,   // [16384][64]
    const _Float16* __restrict__ vT16,  // [8][64][2048]
    const int* __restrict__ mask,       // [8][2048][2048]
    float* __restrict__ attno,          // [16384][64]
    float* __restrict__ aw)             // [8][2048][2048]
{
    __shared__ float sc[RTILE][SCP];        // ~66 KB
    __shared__ _Float16 psh[16][72];        // P chunk as MFMA A-operand (rows 8..15 zero)
    __shared__ float st_il[RTILE];

    const int t = threadIdx.x;
    const int wave = t >> 6, lane = t & 63;
    const int n16 = lane & 15, quad = lane >> 4;
    const int row0 = blockIdx.x * RTILE;          // global row
    const int batch = row0 >> 11, row0s = row0 & (SEQ - 1);

    // zero psh once (rows 8..15 stay zero forever)
    for (int i = t; i < 16 * 36; i += 256) ((float*)psh)[i] = 0.0f;

    // persistent Q A-frags (direct from global, perfectly coalesced)
    {
        // phase 1: raw scaled scores -> sc
        const _Float16* qb = q16 + (size_t)(row0 + n16) * DK + quad * 8;
        f16x8 aq0 = *reinterpret_cast<const f16x8*>(qb);
        f16x8 aq1 = *reinterpret_cast<const f16x8*>(qb + 32);
        for (int c = 0; c < 32; ++c) {
            int key = c * 64 + wave * 16 + n16;
            const _Float16* kb = k16 + (size_t)(batch * SEQ + key) * DK + quad * 8;
            f16x8 b0 = *reinterpret_cast<const f16x8*>(kb);
            f16x8 b1 = *reinterpret_cast<const f16x8*>(kb + 32);
            f32x4 acc = {};
            acc = __builtin_amdgcn_mfma_f32_16x16x32_f16(aq0, b0, acc, 0, 0, 0);
            acc = __builtin_amdgcn_mfma_f32_16x16x32_f16(aq1, b1, acc, 0, 0, 0);
            if (quad < 2) {   // C rows quad*4+reg; only rows 0..7 are real
                int col = c * 64 + wave * 16 + n16;
                #pragma unroll
                for (int r = 0; r < 4; ++r)
                    sc[quad * 4 + r][col] = acc[r] * 0.125f;
            }
        }
    }
    __syncthreads();

    // phase 2: mask fill + softmax stats; sc rewritten as exp(s - m)
    #pragma unroll
    for (int rr = 0; rr < 2; ++rr) {
        int row = wave * 2 + rr;
        const int4* mrow = reinterpret_cast<const int4*>(
            mask + (size_t)batch * SEQ * SEQ + (size_t)(row0s + row) * SEQ);
        float vmax = -3.4e38f;
        #pragma unroll
        for (int it = 0; it < 8; ++it) {
            int j = it * 64 + lane;                 // float4 index within row
            int4  m4 = mrow[j];
            float4 s4 = *reinterpret_cast<float4*>(&sc[row][j * 4]);
            s4.x = (m4.x == 0 || s4.x == 0.0f) ? EPSV : s4.x;
            s4.y = (m4.y == 0 || s4.y == 0.0f) ? EPSV : s4.y;
            s4.z = (m4.z == 0 || s4.z == 0.0f) ? EPSV : s4.z;
            s4.w = (m4.w == 0 || s4.w == 0.0f) ? EPSV : s4.w;
            *reinterpret_cast<float4*>(&sc[row][j * 4]) = s4;
            vmax = fmaxf(vmax, fmaxf(fmaxf(s4.x, s4.y), fmaxf(s4.z, s4.w)));
        }
        #pragma unroll
        for (int off = 32; off; off >>= 1) vmax = fmaxf(vmax, __shfl_xor(vmax, off));
        float vsum = 0.0f;
        #pragma unroll
        for (int it = 0; it < 8; ++it) {
            int j = it * 64 + lane;
            float4 s4 = *reinterpret_cast<float4*>(&sc[row][j * 4]);
            float4 e4 = { __expf(s4.x - vmax), __expf(s4.y - vmax),
                          __expf(s4.z - vmax), __expf(s4.w - vmax) };
            *reinterpret_cast<float4*>(&sc[row][j * 4]) = e4;
            vsum += (e4.x + e4.y) + (e4.z + e4.w);
        }
        #pragma unroll
        for (int off = 32; off; off >>= 1) vsum += __shfl_xor(vsum, off);
        if (lane == 0) st_il[row] = 1.0f / vsum;
    }
    __syncthreads();

    // phase 3: p = e * inv_l -> aw (global) + psh (fp16) -> PV MFMA
    f32x4 oacc = {};
    const int rowp = t >> 5;             // 0..7
    const int col2 = (t & 31) * 2;       // 0..62
    const float il = st_il[rowp];
    float* awrow = aw + (size_t)batch * SEQ * SEQ + (size_t)(row0s + rowp) * SEQ;
    for (int c = 0; c < 32; ++c) {
        int kk = c * 64;
        // prefetch V B-frags (independent of LDS/p) to hide L2 latency
        const _Float16* vb = vT16 + ((size_t)(batch * DK + wave * 16 + n16)) * SEQ + kk + quad * 8;
        f16x8 bv0 = *reinterpret_cast<const f16x8*>(vb);
        f16x8 bv1 = *reinterpret_cast<const f16x8*>(vb + 32);
        // compute p chunk (all 256 threads)
        float2 e2 = *reinterpret_cast<float2*>(&sc[rowp][kk + col2]);
        float2 p2 = { e2.x * il, e2.y * il };
        *reinterpret_cast<float2*>(awrow + kk + col2) = p2;
        f16x2 ph = { (_Float16)p2.x, (_Float16)p2.y };
        *reinterpret_cast<f16x2*>(&psh[rowp][col2]) = ph;
        __syncthreads();
        f16x8 ap0 = *reinterpret_cast<const f16x8*>(&psh[n16][quad * 8]);
        f16x8 ap1 = *reinterpret_cast<const f16x8*>(&psh[n16][32 + quad * 8]);
        oacc = __builtin_amdgcn_mfma_f32_16x16x32_f16(ap0, bv0, oacc, 0, 0, 0);
        oacc = __builtin_amdgcn_mfma_f32_16x16x32_f16(ap1, bv1, oacc, 0, 0, 0);
        __syncthreads();
    }
    if (quad < 2) {
        #pragma unroll
        for (int r = 0; r < 4; ++r) {
            int grow = row0 + quad * 4 + r;
            attno[(size_t)grow * DK + wave * 16 + n16] = oacc[r];
        }
    }
}

// ===================== launch =====================
extern "C" void kernel_launch(void* const* d_in, const int* in_sizes, int n_in,
                              void* d_out, int out_size, void* d_ws, size_t ws_size,
                              hipStream_t stream) {
    const float* query = (const float*)d_in[0];
    const float* key   = (const float*)d_in[1];
    const float* value = (const float*)d_in[2];
    const int*   amask = (const int*)d_in[3];
    const float* Wq = (const float*)d_in[4];
    const float* bq = (const float*)d_in[5];
    const float* Wk = (const float*)d_in[6];
    const float* bk = (const float*)d_in[7];
    const float* Wv = (const float*)d_in[8];
    const float* bv = (const float*)d_in[9];

    float* attno = (float*)d_out;                      // [16384][64]
    float* aw    = attno + (size_t)NROW * DK;          // [8][2048][2048]

    char* ws = (char*)d_ws;
    _Float16* q16  = (_Float16*)(ws);                  // 2 MB
    _Float16* k16  = (_Float16*)(ws + (size_t)2097152);// 2 MB
    _Float16* vT16 = (_Float16*)(ws + (size_t)4194304);// 2 MB
    _Float16* w16  = (_Float16*)(ws + (size_t)6291456);// 192 KB

    wcvt<<<96, 256, 0, stream>>>(Wq, Wk, Wv, w16);
    proj<<<dim3(NROW / 64, 3), 256, 0, stream>>>(query, key, value, w16,
                                                 bq, bk, bv, q16, k16, vT16);
    attn<<<NROW / RTILE, 256, 0, stream>>>(q16, k16, vT16, amask, attno, aw);
}

// Round 2
// 378.638 us; speedup vs baseline: 1.1091x; 1.1091x over previous
//
#include <hip/hip_runtime.h>

// ---- problem dims (hardcoded) ----
#define BATCH 8
#define SEQ   2048
#define DM    512
#define DK    64
#define NROW  (BATCH*SEQ)          // 16384 total rows
#define EPSV  1e-6f

typedef _Float16 f16x8 __attribute__((ext_vector_type(8)));
typedef _Float16 f16x4 __attribute__((ext_vector_type(4)));
typedef _Float16 f16x2 __attribute__((ext_vector_type(2)));
typedef float    f32x4 __attribute__((ext_vector_type(4)));

#define MFMA16(a,b,c) __builtin_amdgcn_mfma_f32_16x16x32_f16(a, b, c, 0, 0, 0)

// ===================== K0: convert W to fp16 =====================
__global__ void wcvt(const float* __restrict__ wq, const float* __restrict__ wk,
                     const float* __restrict__ wv, _Float16* __restrict__ w16) {
    int idx = (blockIdx.x * 256 + threadIdx.x) * 4;   // grid 96 -> 98304 elems
    int z = idx >> 15;                                 // 32768 per matrix
    int off = idx & 32767;
    const float* src = (z == 0) ? wq : ((z == 1) ? wk : wv);
    float4 g = *reinterpret_cast<const float4*>(src + off);
    f16x4 h = { (_Float16)g.x, (_Float16)g.y, (_Float16)g.z, (_Float16)g.w };
    *reinterpret_cast<f16x4*>(w16 + idx) = h;
}

// ===================== K1: QKV projection (MFMA f16) =====================
// out[row][d] = sum_m in[row][m] * W[d][m] + b[d]
// z=0: q16[row][64], z=1: k16[row][64], z=2: vT16[b][d][s] (transposed)
__global__ __launch_bounds__(256) void proj(
    const float* __restrict__ query, const float* __restrict__ key,
    const float* __restrict__ value, const _Float16* __restrict__ w16,
    const float* __restrict__ bq, const float* __restrict__ bk, const float* __restrict__ bv,
    _Float16* __restrict__ q16, _Float16* __restrict__ k16, _Float16* __restrict__ vT16)
{
    __shared__ _Float16 xsh[64][72];   // pitch 72: 16B-aligned rows, conflict-padded

    const int t = threadIdx.x;
    const int wave = t >> 6, lane = t & 63;
    const int n16 = lane & 15, quad = lane >> 4;
    const int z = blockIdx.y;
    const float* in   = (z == 0) ? query : ((z == 1) ? key : value);
    const float* bias = (z == 0) ? bq    : ((z == 1) ? bk  : bv);
    const _Float16* wz = w16 + z * (DK * DM);
    const int row0 = blockIdx.x * 64;

    f32x4 acc[4] = {};   // 4 n-tiles of 16 cols each

    for (int kk = 0; kk < DM; kk += 64) {
        // stage input tile 64x64 fp32 -> fp16 LDS (coalesced float4 reads)
        #pragma unroll
        for (int it = 0; it < 4; ++it) {
            int f = t + it * 256;              // 0..1023 float4 slots
            int row = f >> 4, kq = f & 15;
            float4 g = *reinterpret_cast<const float4*>(in + (size_t)(row0 + row) * DM + kk + kq * 4);
            f16x4 h = { (_Float16)g.x, (_Float16)g.y, (_Float16)g.z, (_Float16)g.w };
            *reinterpret_cast<f16x4*>(&xsh[row][kq * 4]) = h;
        }
        __syncthreads();
        // A-frags for this wave's 16-row slice
        f16x8 a0 = *reinterpret_cast<const f16x8*>(&xsh[wave * 16 + n16][quad * 8]);
        f16x8 a1 = *reinterpret_cast<const f16x8*>(&xsh[wave * 16 + n16][32 + quad * 8]);
        #pragma unroll
        for (int nt = 0; nt < 4; ++nt) {
            const _Float16* bbase = wz + (size_t)(nt * 16 + n16) * DM + kk + quad * 8;
            f16x8 b0 = *reinterpret_cast<const f16x8*>(bbase);
            f16x8 b1 = *reinterpret_cast<const f16x8*>(bbase + 32);
            acc[nt] = MFMA16(a0, b0, acc[nt]);
            acc[nt] = MFMA16(a1, b1, acc[nt]);
        }
        __syncthreads();
    }

    const int batch = row0 >> 11, row0s = row0 & (SEQ - 1);
    if (z < 2) {
        _Float16* out = (z == 0) ? q16 : k16;
        #pragma unroll
        for (int nt = 0; nt < 4; ++nt) {
            float bzv = bias[nt * 16 + n16];
            #pragma unroll
            for (int r = 0; r < 4; ++r) {
                int grow = row0 + wave * 16 + quad * 4 + r;   // C layout: row=quad*4+reg
                out[(size_t)grow * DK + nt * 16 + n16] = (_Float16)(acc[nt][r] + bzv);
            }
        }
    } else {
        // stage transposed tile in LDS: xshT[d][s_local], then coalesced global write
        #pragma unroll
        for (int nt = 0; nt < 4; ++nt) {
            float bzv = bias[nt * 16 + n16];
            #pragma unroll
            for (int r = 0; r < 4; ++r)
                xsh[nt * 16 + n16][wave * 16 + quad * 4 + r] = (_Float16)(acc[nt][r] + bzv);
        }
        __syncthreads();
        // thread t: d = t>>2, s-chunk = (t&3)*16 -> 16 fp16 = two 16B stores, contiguous
        int d = t >> 2, s0 = (t & 3) * 16;
        _Float16* dst = vT16 + ((size_t)(batch * DK + d)) * SEQ + row0s + s0;
        f16x8 h0, h1;
        #pragma unroll
        for (int j = 0; j < 8; ++j) { h0[j] = xsh[d][s0 + j]; h1[j] = xsh[d][s0 + 8 + j]; }
        *reinterpret_cast<f16x8*>(dst)     = h0;
        *reinterpret_cast<f16x8*>(dst + 8) = h1;
    }
}

// ===================== K2: fused attention =====================
// 16 query rows per block (full MFMA M), whole e-row fp16 in LDS,
// barrier-free PV phase (LDS A-operand + streamed global V).
#define RT  16
#define SCH 2056   // fp16 row pitch: 4112 B (16B-aligned)

__global__ __launch_bounds__(256, 2) void attn(
    const _Float16* __restrict__ q16,   // [16384][64]
    const _Float16* __restrict__ k16,   // [16384][64]
    const _Float16* __restrict__ vT16,  // [8][64][2048]
    const int* __restrict__ mask,       // [8][2048][2048]
    float* __restrict__ attno,          // [16384][64]
    float* __restrict__ aw)             // [8][2048][2048]
{
    __shared__ _Float16 sc[RT][SCH];    // scores, then exp(s-m), fp16  (~66 KB)
    __shared__ float st_il[RT];

    const int t = threadIdx.x;
    const int wave = t >> 6, lane = t & 63;
    const int n16 = lane & 15, quad = lane >> 4;
    const int row0 = blockIdx.x * RT;
    const int batch = row0 >> 11, row0s = row0 & (SEQ - 1);

    // ---------- phase 1: scaled scores -> sc (fp16) ----------
    {
        const _Float16* qb = q16 + (size_t)(row0 + n16) * DK + quad * 8;
        f16x8 aq0 = *reinterpret_cast<const f16x8*>(qb);
        f16x8 aq1 = *reinterpret_cast<const f16x8*>(qb + 32);
        const _Float16* kbase = k16 + (size_t)(batch * SEQ) * DK;
        const _Float16* kb = kbase + (size_t)(wave * 16 + n16) * DK + quad * 8;
        f16x8 b0 = *reinterpret_cast<const f16x8*>(kb);
        f16x8 b1 = *reinterpret_cast<const f16x8*>(kb + 32);
        for (int c = 0; c < 32; ++c) {
            f16x8 cb0 = b0, cb1 = b1;
            if (c < 31) {   // software pipeline: next K-frags in flight over this MFMA
                const _Float16* nb = kbase + (size_t)((c + 1) * 64 + wave * 16 + n16) * DK + quad * 8;
                b0 = *reinterpret_cast<const f16x8*>(nb);
                b1 = *reinterpret_cast<const f16x8*>(nb + 32);
            }
            f32x4 acc = {};
            acc = MFMA16(aq0, cb0, acc);
            acc = MFMA16(aq1, cb1, acc);
            int col = c * 64 + wave * 16 + n16;
            #pragma unroll
            for (int r = 0; r < 4; ++r)
                sc[quad * 4 + r][col] = (_Float16)(acc[r] * 0.125f);
        }
    }
    __syncthreads();

    // ---------- phase 2: mask fill + softmax; sc <- exp(s-m) fp16; aw <- p ----------
    #pragma unroll 1
    for (int rr = 0; rr < 4; ++rr) {
        int row = wave * 4 + rr;
        const int4* mrow = reinterpret_cast<const int4*>(
            mask + (size_t)batch * SEQ * SEQ + (size_t)(row0s + row) * SEQ);
        float e[32];
        float vmax = -3.4e38f;
        #pragma unroll
        for (int it = 0; it < 8; ++it) {
            int j = it * 64 + lane;                 // int4 / f16x4 index
            int4  m4 = mrow[j];
            f16x4 s4 = *reinterpret_cast<const f16x4*>(&sc[row][j * 4]);
            float s0 = (float)s4[0], s1 = (float)s4[1], s2 = (float)s4[2], s3 = (float)s4[3];
            s0 = (m4.x == 0 || s0 == 0.0f) ? EPSV : s0;
            s1 = (m4.y == 0 || s1 == 0.0f) ? EPSV : s1;
            s2 = (m4.z == 0 || s2 == 0.0f) ? EPSV : s2;
            s3 = (m4.w == 0 || s3 == 0.0f) ? EPSV : s3;
            e[it * 4 + 0] = s0; e[it * 4 + 1] = s1; e[it * 4 + 2] = s2; e[it * 4 + 3] = s3;
            vmax = fmaxf(vmax, fmaxf(fmaxf(s0, s1), fmaxf(s2, s3)));
        }
        #pragma unroll
        for (int off = 32; off; off >>= 1) vmax = fmaxf(vmax, __shfl_xor(vmax, off));
        float vsum = 0.0f;
        #pragma unroll
        for (int it = 0; it < 8; ++it) {
            int j = it * 64 + lane;
            float e0 = __expf(e[it * 4 + 0] - vmax), e1 = __expf(e[it * 4 + 1] - vmax);
            float e2 = __expf(e[it * 4 + 2] - vmax), e3 = __expf(e[it * 4 + 3] - vmax);
            e[it * 4 + 0] = e0; e[it * 4 + 1] = e1; e[it * 4 + 2] = e2; e[it * 4 + 3] = e3;
            f16x4 h = { (_Float16)e0, (_Float16)e1, (_Float16)e2, (_Float16)e3 };
            *reinterpret_cast<f16x4*>(&sc[row][j * 4]) = h;
            vsum += (e0 + e1) + (e2 + e3);
        }
        #pragma unroll
        for (int off = 32; off; off >>= 1) vsum += __shfl_xor(vsum, off);
        float il = 1.0f / vsum;
        if (lane == 0) st_il[row] = il;
        float* awrow = aw + (size_t)batch * SEQ * SEQ + (size_t)(row0s + row) * SEQ;
        #pragma unroll
        for (int it = 0; it < 8; ++it) {
            int j = it * 64 + lane;
            float4 p4 = { e[it * 4 + 0] * il, e[it * 4 + 1] * il,
                          e[it * 4 + 2] * il, e[it * 4 + 3] * il };
            *reinterpret_cast<float4*>(awrow + j * 4) = p4;
        }
    }
    __syncthreads();

    // ---------- phase 3: O = (E V) * il  — barrier-free MFMA loop ----------
    {
        f32x4 oacc = {};
        const _Float16* vbase = vT16 + ((size_t)(batch * DK + wave * 16 + n16)) * SEQ;
        f16x8 bv0 = *reinterpret_cast<const f16x8*>(vbase + quad * 8);
        f16x8 bv1 = *reinterpret_cast<const f16x8*>(vbase + 32 + quad * 8);
        for (int c = 0; c < 32; ++c) {
            f16x8 cb0 = bv0, cb1 = bv1;
            if (c < 31) {   // pipeline next V-frags over this iteration
                bv0 = *reinterpret_cast<const f16x8*>(vbase + (c + 1) * 64 + quad * 8);
                bv1 = *reinterpret_cast<const f16x8*>(vbase + (c + 1) * 64 + 32 + quad * 8);
            }
            f16x8 a0 = *reinterpret_cast<const f16x8*>(&sc[n16][c * 64 + quad * 8]);
            f16x8 a1 = *reinterpret_cast<const f16x8*>(&sc[n16][c * 64 + 32 + quad * 8]);
            oacc = MFMA16(a0, cb0, oacc);
            oacc = MFMA16(a1, cb1, oacc);
        }
        #pragma unroll
        for (int r = 0; r < 4; ++r) {
            int row = quad * 4 + r;
            attno[(size_t)(row0 + row) * DK + wave * 16 + n16] = oacc[r] * st_il[row];
        }
    }
}

// ===================== launch =====================
extern "C" void kernel_launch(void* const* d_in, const int* in_sizes, int n_in,
                              void* d_out, int out_size, void* d_ws, size_t ws_size,
                              hipStream_t stream) {
    const float* query = (const float*)d_in[0];
    const float* key   = (const float*)d_in[1];
    const float* value = (const float*)d_in[2];
    const int*   amask = (const int*)d_in[3];
    const float* Wq = (const float*)d_in[4];
    const float* bq = (const float*)d_in[5];
    const float* Wk = (const float*)d_in[6];
    const float* bk = (const float*)d_in[7];
    const float* Wv = (const float*)d_in[8];
    const float* bv = (const float*)d_in[9];

    float* attno = (float*)d_out;                      // [16384][64]
    float* aw    = attno + (size_t)NROW * DK;          // [8][2048][2048]

    char* ws = (char*)d_ws;
    _Float16* q16  = (_Float16*)(ws);                  // 2 MB
    _Float16* k16  = (_Float16*)(ws + (size_t)2097152);// 2 MB
    _Float16* vT16 = (_Float16*)(ws + (size_t)4194304);// 2 MB
    _Float16* w16  = (_Float16*)(ws + (size_t)6291456);// 192 KB

    wcvt<<<96, 256, 0, stream>>>(Wq, Wk, Wv, w16);
    proj<<<dim3(NROW / 64, 3), 256, 0, stream>>>(query, key, value, w16,
                                                 bq, bk, bv, q16, k16, vT16);
    attn<<<NROW / RT, 256, 0, stream>>>(q16, k16, vT16, amask, attno, aw);
}

// Round 3
// 377.182 us; speedup vs baseline: 1.1133x; 1.0039x over previous
//
#include <hip/hip_runtime.h>

// ---- problem dims (hardcoded) ----
#define BATCH 8
#define SEQ   2048
#define DM    512
#define DK    64
#define NROW  (BATCH*SEQ)          // 16384 total rows
#define EPSV  1e-6f

typedef _Float16 f16x8 __attribute__((ext_vector_type(8)));
typedef _Float16 f16x4 __attribute__((ext_vector_type(4)));
typedef _Float16 f16x2 __attribute__((ext_vector_type(2)));
typedef float    f32x4 __attribute__((ext_vector_type(4)));

#define MFMA16(a,b,c) __builtin_amdgcn_mfma_f32_16x16x32_f16(a, b, c, 0, 0, 0)

// ===================== K0: convert W to fp16 =====================
__global__ void wcvt(const float* __restrict__ wq, const float* __restrict__ wk,
                     const float* __restrict__ wv, _Float16* __restrict__ w16) {
    int idx = (blockIdx.x * 256 + threadIdx.x) * 4;   // grid 96 -> 98304 elems
    int z = idx >> 15;                                 // 32768 per matrix
    int off = idx & 32767;
    const float* src = (z == 0) ? wq : ((z == 1) ? wk : wv);
    float4 g = *reinterpret_cast<const float4*>(src + off);
    f16x4 h = { (_Float16)g.x, (_Float16)g.y, (_Float16)g.z, (_Float16)g.w };
    *reinterpret_cast<f16x4*>(w16 + idx) = h;
}

// ===================== K1: QKV projection (MFMA f16) =====================
__global__ __launch_bounds__(256) void proj(
    const float* __restrict__ query, const float* __restrict__ key,
    const float* __restrict__ value, const _Float16* __restrict__ w16,
    const float* __restrict__ bq, const float* __restrict__ bk, const float* __restrict__ bv,
    _Float16* __restrict__ q16, _Float16* __restrict__ k16, _Float16* __restrict__ vT16)
{
    __shared__ _Float16 xsh[64][72];   // pitch 72: 16B-aligned rows, conflict-padded

    const int t = threadIdx.x;
    const int wave = t >> 6, lane = t & 63;
    const int n16 = lane & 15, quad = lane >> 4;
    const int z = blockIdx.y;
    const float* in   = (z == 0) ? query : ((z == 1) ? key : value);
    const float* bias = (z == 0) ? bq    : ((z == 1) ? bk  : bv);
    const _Float16* wz = w16 + z * (DK * DM);
    const int row0 = blockIdx.x * 64;

    f32x4 acc[4] = {};   // 4 n-tiles of 16 cols each

    for (int kk = 0; kk < DM; kk += 64) {
        #pragma unroll
        for (int it = 0; it < 4; ++it) {
            int f = t + it * 256;              // 0..1023 float4 slots
            int row = f >> 4, kq = f & 15;
            float4 g = *reinterpret_cast<const float4*>(in + (size_t)(row0 + row) * DM + kk + kq * 4);
            f16x4 h = { (_Float16)g.x, (_Float16)g.y, (_Float16)g.z, (_Float16)g.w };
            *reinterpret_cast<f16x4*>(&xsh[row][kq * 4]) = h;
        }
        __syncthreads();
        f16x8 a0 = *reinterpret_cast<const f16x8*>(&xsh[wave * 16 + n16][quad * 8]);
        f16x8 a1 = *reinterpret_cast<const f16x8*>(&xsh[wave * 16 + n16][32 + quad * 8]);
        #pragma unroll
        for (int nt = 0; nt < 4; ++nt) {
            const _Float16* bbase = wz + (size_t)(nt * 16 + n16) * DM + kk + quad * 8;
            f16x8 b0 = *reinterpret_cast<const f16x8*>(bbase);
            f16x8 b1 = *reinterpret_cast<const f16x8*>(bbase + 32);
            acc[nt] = MFMA16(a0, b0, acc[nt]);
            acc[nt] = MFMA16(a1, b1, acc[nt]);
        }
        __syncthreads();
    }

    const int batch = row0 >> 11, row0s = row0 & (SEQ - 1);
    if (z < 2) {
        _Float16* out = (z == 0) ? q16 : k16;
        #pragma unroll
        for (int nt = 0; nt < 4; ++nt) {
            float bzv = bias[nt * 16 + n16];
            #pragma unroll
            for (int r = 0; r < 4; ++r) {
                int grow = row0 + wave * 16 + quad * 4 + r;   // C layout: row=quad*4+reg
                out[(size_t)grow * DK + nt * 16 + n16] = (_Float16)(acc[nt][r] + bzv);
            }
        }
    } else {
        // stage transposed tile in LDS, then coalesced 32B/thread global write
        #pragma unroll
        for (int nt = 0; nt < 4; ++nt) {
            float bzv = bias[nt * 16 + n16];
            #pragma unroll
            for (int r = 0; r < 4; ++r)
                xsh[nt * 16 + n16][wave * 16 + quad * 4 + r] = (_Float16)(acc[nt][r] + bzv);
        }
        __syncthreads();
        int d = t >> 2, s0 = (t & 3) * 16;
        _Float16* dst = vT16 + ((size_t)(batch * DK + d)) * SEQ + row0s + s0;
        f16x8 h0, h1;
        #pragma unroll
        for (int j = 0; j < 8; ++j) { h0[j] = xsh[d][s0 + j]; h1[j] = xsh[d][s0 + 8 + j]; }
        *reinterpret_cast<f16x8*>(dst)     = h0;
        *reinterpret_cast<f16x8*>(dst + 8) = h1;
    }
}

// ===================== K2: fused attention =====================
// 16 query rows per block, 512 threads (8 waves) for latency hiding.
// Phase 1: 8 waves cover 128 keys/iter. Phase 2: 2 rows/wave.
// Phase 3: key-dim split across wave pairs + LDS reduction.
#define RT  16
#define SCH 2056   // fp16 row pitch: 4112 B (16B-aligned)

__global__ __launch_bounds__(512, 4) void attn(
    const _Float16* __restrict__ q16,   // [16384][64]
    const _Float16* __restrict__ k16,   // [16384][64]
    const _Float16* __restrict__ vT16,  // [8][64][2048]
    const int* __restrict__ mask,       // [8][2048][2048]
    float* __restrict__ attno,          // [16384][64]
    float* __restrict__ aw)             // [8][2048][2048]
{
    __shared__ _Float16 sc[RT][SCH];    // scores, then exp(s-m), fp16  (~66 KB)
    __shared__ float red[4][16][17];    // phase-3 partial-O reduction (padded)
    __shared__ float st_il[RT];

    const int t = threadIdx.x;
    const int wave = t >> 6, lane = t & 63;
    const int n16 = lane & 15, quad = lane >> 4;
    const int row0 = blockIdx.x * RT;
    const int batch = row0 >> 11, row0s = row0 & (SEQ - 1);

    // ---------- phase 1: scaled scores -> sc (fp16); 128 keys/iter ----------
    {
        const _Float16* qb = q16 + (size_t)(row0 + n16) * DK + quad * 8;
        f16x8 aq0 = *reinterpret_cast<const f16x8*>(qb);
        f16x8 aq1 = *reinterpret_cast<const f16x8*>(qb + 32);
        const _Float16* kbase = k16 + (size_t)(batch * SEQ) * DK;
        const _Float16* kb = kbase + (size_t)(wave * 16 + n16) * DK + quad * 8;
        f16x8 b0 = *reinterpret_cast<const f16x8*>(kb);
        f16x8 b1 = *reinterpret_cast<const f16x8*>(kb + 32);
        for (int c = 0; c < 16; ++c) {
            f16x8 cb0 = b0, cb1 = b1;
            if (c < 15) {   // pipeline next K-frags over this MFMA
                const _Float16* nb = kbase + (size_t)((c + 1) * 128 + wave * 16 + n16) * DK + quad * 8;
                b0 = *reinterpret_cast<const f16x8*>(nb);
                b1 = *reinterpret_cast<const f16x8*>(nb + 32);
            }
            f32x4 acc = {};
            acc = MFMA16(aq0, cb0, acc);
            acc = MFMA16(aq1, cb1, acc);
            int col = c * 128 + wave * 16 + n16;
            #pragma unroll
            for (int r = 0; r < 4; ++r)
                sc[quad * 4 + r][col] = (_Float16)(acc[r] * 0.125f);
        }
    }
    __syncthreads();

    // ---------- phase 2: mask fill + softmax; sc <- exp(s-m); aw <- p ----------
    #pragma unroll 1
    for (int rr = 0; rr < 2; ++rr) {
        int row = wave * 2 + rr;
        const int4* mrow = reinterpret_cast<const int4*>(
            mask + (size_t)batch * SEQ * SEQ + (size_t)(row0s + row) * SEQ);
        float e[32];
        float vmax = -3.4e38f;
        #pragma unroll
        for (int it = 0; it < 8; ++it) {
            int j = it * 64 + lane;                 // int4 / f16x4 index
            int4  m4 = mrow[j];
            f16x4 s4 = *reinterpret_cast<const f16x4*>(&sc[row][j * 4]);
            float s0 = (float)s4[0], s1 = (float)s4[1], s2 = (float)s4[2], s3 = (float)s4[3];
            s0 = (m4.x == 0 || s0 == 0.0f) ? EPSV : s0;
            s1 = (m4.y == 0 || s1 == 0.0f) ? EPSV : s1;
            s2 = (m4.z == 0 || s2 == 0.0f) ? EPSV : s2;
            s3 = (m4.w == 0 || s3 == 0.0f) ? EPSV : s3;
            e[it * 4 + 0] = s0; e[it * 4 + 1] = s1; e[it * 4 + 2] = s2; e[it * 4 + 3] = s3;
            vmax = fmaxf(vmax, fmaxf(fmaxf(s0, s1), fmaxf(s2, s3)));
        }
        #pragma unroll
        for (int off = 32; off; off >>= 1) vmax = fmaxf(vmax, __shfl_xor(vmax, off));
        float vsum = 0.0f;
        #pragma unroll
        for (int it = 0; it < 8; ++it) {
            int j = it * 64 + lane;
            float e0 = __expf(e[it * 4 + 0] - vmax), e1 = __expf(e[it * 4 + 1] - vmax);
            float e2 = __expf(e[it * 4 + 2] - vmax), e3 = __expf(e[it * 4 + 3] - vmax);
            e[it * 4 + 0] = e0; e[it * 4 + 1] = e1; e[it * 4 + 2] = e2; e[it * 4 + 3] = e3;
            f16x4 h = { (_Float16)e0, (_Float16)e1, (_Float16)e2, (_Float16)e3 };
            *reinterpret_cast<f16x4*>(&sc[row][j * 4]) = h;
            vsum += (e0 + e1) + (e2 + e3);
        }
        #pragma unroll
        for (int off = 32; off; off >>= 1) vsum += __shfl_xor(vsum, off);
        float il = 1.0f / vsum;
        if (lane == 0) st_il[row] = il;
        float* awrow = aw + (size_t)batch * SEQ * SEQ + (size_t)(row0s + row) * SEQ;
        #pragma unroll
        for (int it = 0; it < 8; ++it) {
            int j = it * 64 + lane;
            float4 p4 = { e[it * 4 + 0] * il, e[it * 4 + 1] * il,
                          e[it * 4 + 2] * il, e[it * 4 + 3] * il };
            *reinterpret_cast<float4*>(awrow + j * 4) = p4;
        }
    }
    __syncthreads();

    // ---------- phase 3: O = (E V) * il — key-split across wave pairs ----------
    {
        const int dblk = wave & 3, khalf = wave >> 2;
        f32x4 oacc = {};
        const _Float16* vbase = vT16 + ((size_t)(batch * DK + dblk * 16 + n16)) * SEQ
                              + khalf * 1024;
        const _Float16* scrow = &sc[n16][khalf * 1024];
        f16x8 bv0 = *reinterpret_cast<const f16x8*>(vbase + quad * 8);
        f16x8 bv1 = *reinterpret_cast<const f16x8*>(vbase + 32 + quad * 8);
        for (int c = 0; c < 16; ++c) {
            f16x8 cb0 = bv0, cb1 = bv1;
            if (c < 15) {   // pipeline next V-frags
                bv0 = *reinterpret_cast<const f16x8*>(vbase + (c + 1) * 64 + quad * 8);
                bv1 = *reinterpret_cast<const f16x8*>(vbase + (c + 1) * 64 + 32 + quad * 8);
            }
            f16x8 a0 = *reinterpret_cast<const f16x8*>(scrow + c * 64 + quad * 8);
            f16x8 a1 = *reinterpret_cast<const f16x8*>(scrow + c * 64 + 32 + quad * 8);
            oacc = MFMA16(a0, cb0, oacc);
            oacc = MFMA16(a1, cb1, oacc);
        }
        if (khalf == 1) {
            #pragma unroll
            for (int r = 0; r < 4; ++r)
                red[dblk][quad * 4 + r][n16] = oacc[r];
        }
        __syncthreads();
        if (khalf == 0) {
            #pragma unroll
            for (int r = 0; r < 4; ++r) {
                int row = quad * 4 + r;
                float o = oacc[r] + red[dblk][row][n16];
                attno[(size_t)(row0 + row) * DK + dblk * 16 + n16] = o * st_il[row];
            }
        }
    }
}

// ===================== launch =====================
extern "C" void kernel_launch(void* const* d_in, const int* in_sizes, int n_in,
                              void* d_out, int out_size, void* d_ws, size_t ws_size,
                              hipStream_t stream) {
    const float* query = (const float*)d_in[0];
    const float* key   = (const float*)d_in[1];
    const float* value = (const float*)d_in[2];
    const int*   amask = (const int*)d_in[3];
    const float* Wq = (const float*)d_in[4];
    const float* bq = (const float*)d_in[5];
    const float* Wk = (const float*)d_in[6];
    const float* bk = (const float*)d_in[7];
    const float* Wv = (const float*)d_in[8];
    const float* bv = (const float*)d_in[9];

    float* attno = (float*)d_out;                      // [16384][64]
    float* aw    = attno + (size_t)NROW * DK;          // [8][2048][2048]

    char* ws = (char*)d_ws;
    _Float16* q16  = (_Float16*)(ws);                  // 2 MB
    _Float16* k16  = (_Float16*)(ws + (size_t)2097152);// 2 MB
    _Float16* vT16 = (_Float16*)(ws + (size_t)4194304);// 2 MB
    _Float16* w16  = (_Float16*)(ws + (size_t)6291456);// 192 KB

    wcvt<<<96, 256, 0, stream>>>(Wq, Wk, Wv, w16);
    proj<<<dim3(NROW / 64, 3), 256, 0, stream>>>(query, key, value, w16,
                                                 bq, bk, bv, q16, k16, vT16);
    attn<<<NROW / RT, 512, 0, stream>>>(q16, k16, vT16, amask, attno, aw);
}

// Round 4
// 369.503 us; speedup vs baseline: 1.1365x; 1.0208x over previous
//
#include <hip/hip_runtime.h>

// ---- problem dims (hardcoded) ----
#define BATCH 8
#define SEQ   2048
#define DM    512
#define DK    64
#define NROW  (BATCH*SEQ)          // 16384 total rows
#define EPSV  1e-6f

typedef _Float16 f16x8 __attribute__((ext_vector_type(8)));
typedef _Float16 f16x4 __attribute__((ext_vector_type(4)));
typedef float    f32x4 __attribute__((ext_vector_type(4)));

#define MFMA16(a,b,c) __builtin_amdgcn_mfma_f32_16x16x32_f16(a, b, c, 0, 0, 0)

// ===================== K0: convert W to fp16 =====================
__global__ void wcvt(const float* __restrict__ wq, const float* __restrict__ wk,
                     const float* __restrict__ wv, _Float16* __restrict__ w16) {
    int idx = (blockIdx.x * 256 + threadIdx.x) * 4;   // grid 96 -> 98304 elems
    int z = idx >> 15;                                 // 32768 per matrix
    int off = idx & 32767;
    const float* src = (z == 0) ? wq : ((z == 1) ? wk : wv);
    float4 g = *reinterpret_cast<const float4*>(src + off);
    f16x4 h = { (_Float16)g.x, (_Float16)g.y, (_Float16)g.z, (_Float16)g.w };
    *reinterpret_cast<f16x4*>(w16 + idx) = h;
}

// ===================== K1: QKV projection (MFMA f16, barrier-free) =====================
// A-frags loaded directly from global fp32 (A[m=n16][k=quad*8+j] is 8 consecutive
// floats of row m) and converted in registers — no LDS staging, no main-loop barriers.
__global__ __launch_bounds__(256) void proj(
    const float* __restrict__ query, const float* __restrict__ key,
    const float* __restrict__ value, const _Float16* __restrict__ w16,
    const float* __restrict__ bq, const float* __restrict__ bk, const float* __restrict__ bv,
    _Float16* __restrict__ q16, _Float16* __restrict__ k16, _Float16* __restrict__ vT16)
{
    __shared__ _Float16 xsh[64][72];   // only for the vT transpose epilogue

    const int t = threadIdx.x;
    const int wave = t >> 6, lane = t & 63;
    const int n16 = lane & 15, quad = lane >> 4;
    const int z = blockIdx.y;
    const float* in   = (z == 0) ? query : ((z == 1) ? key : value);
    const float* bias = (z == 0) ? bq    : ((z == 1) ? bk  : bv);
    const _Float16* wz = w16 + z * (DK * DM);
    const int row0 = blockIdx.x * 64;
    const float* abase = in + (size_t)(row0 + wave * 16 + n16) * DM + quad * 8;

    f32x4 acc[4] = {};   // 4 n-tiles of 16 cols each

    // depth-1 prefetch of the 4 float4 A-pieces (k 0..31 and 32..63 of this row)
    float4 p0 = *reinterpret_cast<const float4*>(abase);
    float4 p1 = *reinterpret_cast<const float4*>(abase + 4);
    float4 p2 = *reinterpret_cast<const float4*>(abase + 32);
    float4 p3 = *reinterpret_cast<const float4*>(abase + 36);

    #pragma unroll 2
    for (int kk = 0; kk < DM; kk += 64) {
        f16x8 a0 = { (_Float16)p0.x, (_Float16)p0.y, (_Float16)p0.z, (_Float16)p0.w,
                     (_Float16)p1.x, (_Float16)p1.y, (_Float16)p1.z, (_Float16)p1.w };
        f16x8 a1 = { (_Float16)p2.x, (_Float16)p2.y, (_Float16)p2.z, (_Float16)p2.w,
                     (_Float16)p3.x, (_Float16)p3.y, (_Float16)p3.z, (_Float16)p3.w };
        if (kk < DM - 64) {
            p0 = *reinterpret_cast<const float4*>(abase + kk + 64);
            p1 = *reinterpret_cast<const float4*>(abase + kk + 68);
            p2 = *reinterpret_cast<const float4*>(abase + kk + 96);
            p3 = *reinterpret_cast<const float4*>(abase + kk + 100);
        }
        #pragma unroll
        for (int nt = 0; nt < 4; ++nt) {
            const _Float16* bbase = wz + (size_t)(nt * 16 + n16) * DM + kk + quad * 8;
            f16x8 b0 = *reinterpret_cast<const f16x8*>(bbase);
            f16x8 b1 = *reinterpret_cast<const f16x8*>(bbase + 32);
            acc[nt] = MFMA16(a0, b0, acc[nt]);
            acc[nt] = MFMA16(a1, b1, acc[nt]);
        }
    }

    const int batch = row0 >> 11, row0s = row0 & (SEQ - 1);
    if (z < 2) {
        _Float16* out = (z == 0) ? q16 : k16;
        #pragma unroll
        for (int nt = 0; nt < 4; ++nt) {
            float bzv = bias[nt * 16 + n16];
            #pragma unroll
            for (int r = 0; r < 4; ++r) {
                int grow = row0 + wave * 16 + quad * 4 + r;   // C layout: row=quad*4+reg
                out[(size_t)grow * DK + nt * 16 + n16] = (_Float16)(acc[nt][r] + bzv);
            }
        }
    } else {
        // stage transposed tile in LDS, then coalesced 32B/thread global write
        #pragma unroll
        for (int nt = 0; nt < 4; ++nt) {
            float bzv = bias[nt * 16 + n16];
            #pragma unroll
            for (int r = 0; r < 4; ++r)
                xsh[nt * 16 + n16][wave * 16 + quad * 4 + r] = (_Float16)(acc[nt][r] + bzv);
        }
        __syncthreads();
        int d = t >> 2, s0 = (t & 3) * 16;
        _Float16* dst = vT16 + ((size_t)(batch * DK + d)) * SEQ + row0s + s0;
        f16x8 h0, h1;
        #pragma unroll
        for (int j = 0; j < 8; ++j) { h0[j] = xsh[d][s0 + j]; h1[j] = xsh[d][s0 + 8 + j]; }
        *reinterpret_cast<f16x8*>(dst)     = h0;
        *reinterpret_cast<f16x8*>(dst + 8) = h1;
    }
}

// ===================== K2: fused attention =====================
// 16 query rows / block, 512 threads. Phase 2 is three lane-private LDS passes —
// no e[32] register array, no scratch spill (round-3 VGPR=52 proved spilling).
#define RT  16
#define SCH 2056   // fp16 row pitch: 4112 B (16B-aligned)

__global__ __launch_bounds__(512, 4) void attn(
    const _Float16* __restrict__ q16,   // [16384][64]
    const _Float16* __restrict__ k16,   // [16384][64]
    const _Float16* __restrict__ vT16,  // [8][64][2048]
    const int* __restrict__ mask,       // [8][2048][2048]
    float* __restrict__ attno,          // [16384][64]
    float* __restrict__ aw)             // [8][2048][2048]
{
    __shared__ _Float16 sc[RT][SCH];    // scores -> masked s -> exp(s-m), fp16 (~66 KB)
    __shared__ float red[4][16][17];    // phase-3 partial-O reduction (padded)
    __shared__ float st_il[RT];

    const int t = threadIdx.x;
    const int wave = t >> 6, lane = t & 63;
    const int n16 = lane & 15, quad = lane >> 4;
    const int row0 = blockIdx.x * RT;
    const int batch = row0 >> 11, row0s = row0 & (SEQ - 1);

    // ---------- phase 1: scaled scores -> sc (fp16); 128 keys/iter ----------
    {
        const _Float16* qb = q16 + (size_t)(row0 + n16) * DK + quad * 8;
        f16x8 aq0 = *reinterpret_cast<const f16x8*>(qb);
        f16x8 aq1 = *reinterpret_cast<const f16x8*>(qb + 32);
        const _Float16* kbase = k16 + (size_t)(batch * SEQ) * DK;
        const _Float16* kb = kbase + (size_t)(wave * 16 + n16) * DK + quad * 8;
        f16x8 b0 = *reinterpret_cast<const f16x8*>(kb);
        f16x8 b1 = *reinterpret_cast<const f16x8*>(kb + 32);
        for (int c = 0; c < 16; ++c) {
            f16x8 cb0 = b0, cb1 = b1;
            if (c < 15) {   // pipeline next K-frags over this MFMA
                const _Float16* nb = kbase + (size_t)((c + 1) * 128 + wave * 16 + n16) * DK + quad * 8;
                b0 = *reinterpret_cast<const f16x8*>(nb);
                b1 = *reinterpret_cast<const f16x8*>(nb + 32);
            }
            f32x4 acc = {};
            acc = MFMA16(aq0, cb0, acc);
            acc = MFMA16(aq1, cb1, acc);
            int col = c * 128 + wave * 16 + n16;
            #pragma unroll
            for (int r = 0; r < 4; ++r)
                sc[quad * 4 + r][col] = (_Float16)(acc[r] * 0.125f);
        }
    }
    __syncthreads();

    // ---------- phase 2: three lane-private LDS passes per row ----------
    #pragma unroll 1
    for (int rr = 0; rr < 2; ++rr) {
        int row = wave * 2 + rr;
        const int4* mrow = reinterpret_cast<const int4*>(
            mask + (size_t)batch * SEQ * SEQ + (size_t)(row0s + row) * SEQ);

        // pass A: mask/eps fill -> writeback fp16; track max
        float vmax = -3.4e38f;
        #pragma unroll
        for (int it = 0; it < 8; ++it) {
            int j = it * 64 + lane;                 // int4 / f16x4 index
            int4  m4 = mrow[j];
            f16x4 s4 = *reinterpret_cast<const f16x4*>(&sc[row][j * 4]);
            float s0 = (float)s4[0], s1 = (float)s4[1], s2 = (float)s4[2], s3 = (float)s4[3];
            s0 = (m4.x == 0 || s0 == 0.0f) ? EPSV : s0;
            s1 = (m4.y == 0 || s1 == 0.0f) ? EPSV : s1;
            s2 = (m4.z == 0 || s2 == 0.0f) ? EPSV : s2;
            s3 = (m4.w == 0 || s3 == 0.0f) ? EPSV : s3;
            f16x4 h = { (_Float16)s0, (_Float16)s1, (_Float16)s2, (_Float16)s3 };
            *reinterpret_cast<f16x4*>(&sc[row][j * 4]) = h;
            vmax = fmaxf(vmax, fmaxf(fmaxf(s0, s1), fmaxf(s2, s3)));
        }
        #pragma unroll
        for (int off = 32; off; off >>= 1) vmax = fmaxf(vmax, __shfl_xor(vmax, off));

        // pass B: exp(s - m) -> writeback fp16; track sum
        float vsum = 0.0f;
        #pragma unroll
        for (int it = 0; it < 8; ++it) {
            int j = it * 64 + lane;
            f16x4 s4 = *reinterpret_cast<const f16x4*>(&sc[row][j * 4]);
            float e0 = __expf((float)s4[0] - vmax), e1 = __expf((float)s4[1] - vmax);
            float e2 = __expf((float)s4[2] - vmax), e3 = __expf((float)s4[3] - vmax);
            f16x4 h = { (_Float16)e0, (_Float16)e1, (_Float16)e2, (_Float16)e3 };
            *reinterpret_cast<f16x4*>(&sc[row][j * 4]) = h;
            vsum += (e0 + e1) + (e2 + e3);
        }
        #pragma unroll
        for (int off = 32; off; off >>= 1) vsum += __shfl_xor(vsum, off);
        float il = 1.0f / vsum;
        if (lane == 0) st_il[row] = il;

        // pass C: p = e * il -> aw (coalesced float4)
        float* awrow = aw + (size_t)batch * SEQ * SEQ + (size_t)(row0s + row) * SEQ;
        #pragma unroll
        for (int it = 0; it < 8; ++it) {
            int j = it * 64 + lane;
            f16x4 e4 = *reinterpret_cast<const f16x4*>(&sc[row][j * 4]);
            float4 p4 = { (float)e4[0] * il, (float)e4[1] * il,
                          (float)e4[2] * il, (float)e4[3] * il };
            *reinterpret_cast<float4*>(awrow + j * 4) = p4;
        }
    }
    __syncthreads();

    // ---------- phase 3: O = (E V) * il — key-split across wave pairs ----------
    {
        const int dblk = wave & 3, khalf = wave >> 2;
        f32x4 oacc = {};
        const _Float16* vbase = vT16 + ((size_t)(batch * DK + dblk * 16 + n16)) * SEQ
                              + khalf * 1024;
        const _Float16* scrow = &sc[n16][khalf * 1024];
        f16x8 bv0 = *reinterpret_cast<const f16x8*>(vbase + quad * 8);
        f16x8 bv1 = *reinterpret_cast<const f16x8*>(vbase + 32 + quad * 8);
        for (int c = 0; c < 16; ++c) {
            f16x8 cb0 = bv0, cb1 = bv1;
            if (c < 15) {   // pipeline next V-frags
                bv0 = *reinterpret_cast<const f16x8*>(vbase + (c + 1) * 64 + quad * 8);
                bv1 = *reinterpret_cast<const f16x8*>(vbase + (c + 1) * 64 + 32 + quad * 8);
            }
            f16x8 a0 = *reinterpret_cast<const f16x8*>(scrow + c * 64 + quad * 8);
            f16x8 a1 = *reinterpret_cast<const f16x8*>(scrow + c * 64 + 32 + quad * 8);
            oacc = MFMA16(a0, cb0, oacc);
            oacc = MFMA16(a1, cb1, oacc);
        }
        if (khalf == 1) {
            #pragma unroll
            for (int r = 0; r < 4; ++r)
                red[dblk][quad * 4 + r][n16] = oacc[r];
        }
        __syncthreads();
        if (khalf == 0) {
            #pragma unroll
            for (int r = 0; r < 4; ++r) {
                int row = quad * 4 + r;
                float o = oacc[r] + red[dblk][row][n16];
                attno[(size_t)(row0 + row) * DK + dblk * 16 + n16] = o * st_il[row];
            }
        }
    }
}

// ===================== launch =====================
extern "C" void kernel_launch(void* const* d_in, const int* in_sizes, int n_in,
                              void* d_out, int out_size, void* d_ws, size_t ws_size,
                              hipStream_t stream) {
    const float* query = (const float*)d_in[0];
    const float* key   = (const float*)d_in[1];
    const float* value = (const float*)d_in[2];
    const int*   amask = (const int*)d_in[3];
    const float* Wq = (const float*)d_in[4];
    const float* bq = (const float*)d_in[5];
    const float* Wk = (const float*)d_in[6];
    const float* bk = (const float*)d_in[7];
    const float* Wv = (const float*)d_in[8];
    const float* bv = (const float*)d_in[9];

    float* attno = (float*)d_out;                      // [16384][64]
    float* aw    = attno + (size_t)NROW * DK;          // [8][2048][2048]

    char* ws = (char*)d_ws;
    _Float16* q16  = (_Float16*)(ws);                  // 2 MB
    _Float16* k16  = (_Float16*)(ws + (size_t)2097152);// 2 MB
    _Float16* vT16 = (_Float16*)(ws + (size_t)4194304);// 2 MB
    _Float16* w16  = (_Float16*)(ws + (size_t)6291456);// 192 KB

    wcvt<<<96, 256, 0, stream>>>(Wq, Wk, Wv, w16);
    proj<<<dim3(NROW / 64, 3), 256, 0, stream>>>(query, key, value, w16,
                                                 bq, bk, bv, q16, k16, vT16);
    attn<<<NROW / RT, 512, 0, stream>>>(q16, k16, vT16, amask, attno, aw);
}

// Round 5
// 368.681 us; speedup vs baseline: 1.1390x; 1.0022x over previous
//
#include <hip/hip_runtime.h>

// ---- problem dims (hardcoded) ----
#define BATCH 8
#define SEQ   2048
#define DM    512
#define DK    64
#define NROW  (BATCH*SEQ)          // 16384 total rows
#define EPSV  1e-6f

typedef _Float16 f16x8 __attribute__((ext_vector_type(8)));
typedef _Float16 f16x4 __attribute__((ext_vector_type(4)));
typedef float    f32x4 __attribute__((ext_vector_type(4)));

#define MFMA16(a,b,c) __builtin_amdgcn_mfma_f32_16x16x32_f16(a, b, c, 0, 0, 0)

// ===================== K0: convert W to fp16 =====================
__global__ void wcvt(const float* __restrict__ wq, const float* __restrict__ wk,
                     const float* __restrict__ wv, _Float16* __restrict__ w16) {
    int idx = (blockIdx.x * 256 + threadIdx.x) * 4;   // grid 96 -> 98304 elems
    int z = idx >> 15;                                 // 32768 per matrix
    int off = idx & 32767;
    const float* src = (z == 0) ? wq : ((z == 1) ? wk : wv);
    float4 g = *reinterpret_cast<const float4*>(src + off);
    f16x4 h = { (_Float16)g.x, (_Float16)g.y, (_Float16)g.z, (_Float16)g.w };
    *reinterpret_cast<f16x4*>(w16 + idx) = h;
}

// ===================== K1: QKV projection (MFMA f16, barrier-free) =====================
__global__ __launch_bounds__(256) void proj(
    const float* __restrict__ query, const float* __restrict__ key,
    const float* __restrict__ value, const _Float16* __restrict__ w16,
    const float* __restrict__ bq, const float* __restrict__ bk, const float* __restrict__ bv,
    _Float16* __restrict__ q16, _Float16* __restrict__ k16, _Float16* __restrict__ vT16)
{
    __shared__ _Float16 xsh[64][72];   // only for the vT transpose epilogue

    const int t = threadIdx.x;
    const int wave = t >> 6, lane = t & 63;
    const int n16 = lane & 15, quad = lane >> 4;
    const int z = blockIdx.y;
    const float* in   = (z == 0) ? query : ((z == 1) ? key : value);
    const float* bias = (z == 0) ? bq    : ((z == 1) ? bk  : bv);
    const _Float16* wz = w16 + z * (DK * DM);
    const int row0 = blockIdx.x * 64;
    const float* abase = in + (size_t)(row0 + wave * 16 + n16) * DM + quad * 8;

    f32x4 acc[4] = {};   // 4 n-tiles of 16 cols each

    float4 p0 = *reinterpret_cast<const float4*>(abase);
    float4 p1 = *reinterpret_cast<const float4*>(abase + 4);
    float4 p2 = *reinterpret_cast<const float4*>(abase + 32);
    float4 p3 = *reinterpret_cast<const float4*>(abase + 36);

    #pragma unroll 2
    for (int kk = 0; kk < DM; kk += 64) {
        f16x8 a0 = { (_Float16)p0.x, (_Float16)p0.y, (_Float16)p0.z, (_Float16)p0.w,
                     (_Float16)p1.x, (_Float16)p1.y, (_Float16)p1.z, (_Float16)p1.w };
        f16x8 a1 = { (_Float16)p2.x, (_Float16)p2.y, (_Float16)p2.z, (_Float16)p2.w,
                     (_Float16)p3.x, (_Float16)p3.y, (_Float16)p3.z, (_Float16)p3.w };
        if (kk < DM - 64) {
            p0 = *reinterpret_cast<const float4*>(abase + kk + 64);
            p1 = *reinterpret_cast<const float4*>(abase + kk + 68);
            p2 = *reinterpret_cast<const float4*>(abase + kk + 96);
            p3 = *reinterpret_cast<const float4*>(abase + kk + 100);
        }
        #pragma unroll
        for (int nt = 0; nt < 4; ++nt) {
            const _Float16* bbase = wz + (size_t)(nt * 16 + n16) * DM + kk + quad * 8;
            f16x8 b0 = *reinterpret_cast<const f16x8*>(bbase);
            f16x8 b1 = *reinterpret_cast<const f16x8*>(bbase + 32);
            acc[nt] = MFMA16(a0, b0, acc[nt]);
            acc[nt] = MFMA16(a1, b1, acc[nt]);
        }
    }

    const int batch = row0 >> 11, row0s = row0 & (SEQ - 1);
    if (z < 2) {
        _Float16* out = (z == 0) ? q16 : k16;
        #pragma unroll
        for (int nt = 0; nt < 4; ++nt) {
            float bzv = bias[nt * 16 + n16];
            #pragma unroll
            for (int r = 0; r < 4; ++r) {
                int grow = row0 + wave * 16 + quad * 4 + r;   // C layout: row=quad*4+reg
                out[(size_t)grow * DK + nt * 16 + n16] = (_Float16)(acc[nt][r] + bzv);
            }
        }
    } else {
        #pragma unroll
        for (int nt = 0; nt < 4; ++nt) {
            float bzv = bias[nt * 16 + n16];
            #pragma unroll
            for (int r = 0; r < 4; ++r)
                xsh[nt * 16 + n16][wave * 16 + quad * 4 + r] = (_Float16)(acc[nt][r] + bzv);
        }
        __syncthreads();
        int d = t >> 2, s0 = (t & 3) * 16;
        _Float16* dst = vT16 + ((size_t)(batch * DK + d)) * SEQ + row0s + s0;
        f16x8 h0, h1;
        #pragma unroll
        for (int j = 0; j < 8; ++j) { h0[j] = xsh[d][s0 + j]; h1[j] = xsh[d][s0 + 8 + j]; }
        *reinterpret_cast<f16x8*>(dst)     = h0;
        *reinterpret_cast<f16x8*>(dst + 8) = h1;
    }
}

// ===================== K2: fused attention =====================
// Latency-hiding round: mask prefetched to register bitmasks before phase 1,
// depth-2 pipelines in phases 1/3, nontemporal aw stores.
#define RT  16
#define SCH 2056   // fp16 row pitch: 4112 B (16B-aligned)

__global__ __launch_bounds__(512, 4) void attn(
    const _Float16* __restrict__ q16,   // [16384][64]
    const _Float16* __restrict__ k16,   // [16384][64]
    const _Float16* __restrict__ vT16,  // [8][64][2048]
    const int* __restrict__ mask,       // [8][2048][2048]
    float* __restrict__ attno,          // [16384][64]
    float* __restrict__ aw)             // [8][2048][2048]
{
    __shared__ _Float16 sc[RT][SCH];    // scores -> masked s -> exp(s-m), fp16 (~66 KB)
    __shared__ float red[4][16][17];    // phase-3 partial-O reduction (padded)
    __shared__ float st_il[RT];

    const int t = threadIdx.x;
    const int wave = t >> 6, lane = t & 63;
    const int n16 = lane & 15, quad = lane >> 4;
    const int row0 = blockIdx.x * RT;
    const int batch = row0 >> 11, row0s = row0 & (SEQ - 1);

    // ---------- phase 0: mask -> register bitmasks (hides L3/HBM latency under QK) ----------
    // this lane covers, for rows wave*2 / wave*2+1, keys {it*256 + lane*4 .. +3}, it=0..7
    unsigned int mb0 = 0, mb1 = 0;
    {
        const int4* mr0 = reinterpret_cast<const int4*>(
            mask + (size_t)batch * SEQ * SEQ + (size_t)(row0s + wave * 2) * SEQ);
        const int4* mr1 = mr0 + SEQ / 4;
        #pragma unroll
        for (int it = 0; it < 8; ++it) {
            int4 a = mr0[it * 64 + lane];
            int4 b = mr1[it * 64 + lane];
            mb0 |= ((a.x != 0) ? 1u : 0u) << (it * 4 + 0);
            mb0 |= ((a.y != 0) ? 1u : 0u) << (it * 4 + 1);
            mb0 |= ((a.z != 0) ? 1u : 0u) << (it * 4 + 2);
            mb0 |= ((a.w != 0) ? 1u : 0u) << (it * 4 + 3);
            mb1 |= ((b.x != 0) ? 1u : 0u) << (it * 4 + 0);
            mb1 |= ((b.y != 0) ? 1u : 0u) << (it * 4 + 1);
            mb1 |= ((b.z != 0) ? 1u : 0u) << (it * 4 + 2);
            mb1 |= ((b.w != 0) ? 1u : 0u) << (it * 4 + 3);
        }
    }

    // ---------- phase 1: scaled scores -> sc (fp16); 128 keys/iter, depth-2 pipe ----------
    {
        const _Float16* qb = q16 + (size_t)(row0 + n16) * DK + quad * 8;
        f16x8 aq0 = *reinterpret_cast<const f16x8*>(qb);
        f16x8 aq1 = *reinterpret_cast<const f16x8*>(qb + 32);
        const _Float16* kbase = k16 + (size_t)(batch * SEQ) * DK
                              + (size_t)(wave * 16 + n16) * DK + quad * 8;
        f16x8 b0[2], b1[2];
        b0[0] = *reinterpret_cast<const f16x8*>(kbase);
        b1[0] = *reinterpret_cast<const f16x8*>(kbase + 32);
        b0[1] = *reinterpret_cast<const f16x8*>(kbase + 128 * DK);
        b1[1] = *reinterpret_cast<const f16x8*>(kbase + 128 * DK + 32);
        #pragma unroll
        for (int c = 0; c < 16; ++c) {
            int cur = c & 1;
            f16x8 cb0 = b0[cur], cb1 = b1[cur];
            if (c < 14) {   // depth-2: keep two chunk-loads in flight
                b0[cur] = *reinterpret_cast<const f16x8*>(kbase + (size_t)(c + 2) * 128 * DK);
                b1[cur] = *reinterpret_cast<const f16x8*>(kbase + (size_t)(c + 2) * 128 * DK + 32);
            }
            f32x4 acc = {};
            acc = MFMA16(aq0, cb0, acc);
            acc = MFMA16(aq1, cb1, acc);
            int col = c * 128 + wave * 16 + n16;
            #pragma unroll
            for (int r = 0; r < 4; ++r)
                sc[quad * 4 + r][col] = (_Float16)(acc[r] * 0.125f);
        }
    }
    __syncthreads();

    // ---------- phase 2: pure LDS/VALU softmax (mask already in registers) ----------
    #pragma unroll 1
    for (int rr = 0; rr < 2; ++rr) {
        int row = wave * 2 + rr;
        unsigned int mb = rr ? mb1 : mb0;

        // pass A: mask/eps fill -> writeback fp16; track max
        float vmax = -3.4e38f;
        #pragma unroll
        for (int it = 0; it < 8; ++it) {
            int j = it * 64 + lane;
            f16x4 s4 = *reinterpret_cast<const f16x4*>(&sc[row][j * 4]);
            float s0 = (float)s4[0], s1 = (float)s4[1], s2 = (float)s4[2], s3 = (float)s4[3];
            s0 = (!((mb >> (it * 4 + 0)) & 1u) || s0 == 0.0f) ? EPSV : s0;
            s1 = (!((mb >> (it * 4 + 1)) & 1u) || s1 == 0.0f) ? EPSV : s1;
            s2 = (!((mb >> (it * 4 + 2)) & 1u) || s2 == 0.0f) ? EPSV : s2;
            s3 = (!((mb >> (it * 4 + 3)) & 1u) || s3 == 0.0f) ? EPSV : s3;
            f16x4 h = { (_Float16)s0, (_Float16)s1, (_Float16)s2, (_Float16)s3 };
            *reinterpret_cast<f16x4*>(&sc[row][j * 4]) = h;
            vmax = fmaxf(vmax, fmaxf(fmaxf(s0, s1), fmaxf(s2, s3)));
        }
        #pragma unroll
        for (int off = 32; off; off >>= 1) vmax = fmaxf(vmax, __shfl_xor(vmax, off));

        // pass B: exp(s - m) -> writeback fp16; track sum
        float vsum = 0.0f;
        #pragma unroll
        for (int it = 0; it < 8; ++it) {
            int j = it * 64 + lane;
            f16x4 s4 = *reinterpret_cast<const f16x4*>(&sc[row][j * 4]);
            float e0 = __expf((float)s4[0] - vmax), e1 = __expf((float)s4[1] - vmax);
            float e2 = __expf((float)s4[2] - vmax), e3 = __expf((float)s4[3] - vmax);
            f16x4 h = { (_Float16)e0, (_Float16)e1, (_Float16)e2, (_Float16)e3 };
            *reinterpret_cast<f16x4*>(&sc[row][j * 4]) = h;
            vsum += (e0 + e1) + (e2 + e3);
        }
        #pragma unroll
        for (int off = 32; off; off >>= 1) vsum += __shfl_xor(vsum, off);
        float il = 1.0f / vsum;
        if (lane == 0) st_il[row] = il;

        // pass C: p = e * il -> aw (nontemporal float4 — write-once data)
        float* awrow = aw + (size_t)batch * SEQ * SEQ + (size_t)(row0s + row) * SEQ;
        #pragma unroll
        for (int it = 0; it < 8; ++it) {
            int j = it * 64 + lane;
            f16x4 e4 = *reinterpret_cast<const f16x4*>(&sc[row][j * 4]);
            f32x4 p4 = { (float)e4[0] * il, (float)e4[1] * il,
                         (float)e4[2] * il, (float)e4[3] * il };
            __builtin_nontemporal_store(p4, reinterpret_cast<f32x4*>(awrow + j * 4));
        }
    }
    __syncthreads();

    // ---------- phase 3: O = (E V) * il — key-split, depth-2 pipe ----------
    {
        const int dblk = wave & 3, khalf = wave >> 2;
        f32x4 oacc = {};
        const _Float16* vbase = vT16 + ((size_t)(batch * DK + dblk * 16 + n16)) * SEQ
                              + khalf * 1024 + quad * 8;
        const _Float16* scrow = &sc[n16][khalf * 1024];
        f16x8 bv0[2], bv1[2];
        bv0[0] = *reinterpret_cast<const f16x8*>(vbase);
        bv1[0] = *reinterpret_cast<const f16x8*>(vbase + 32);
        bv0[1] = *reinterpret_cast<const f16x8*>(vbase + 64);
        bv1[1] = *reinterpret_cast<const f16x8*>(vbase + 96);
        #pragma unroll
        for (int c = 0; c < 16; ++c) {
            int cur = c & 1;
            f16x8 cb0 = bv0[cur], cb1 = bv1[cur];
            if (c < 14) {
                bv0[cur] = *reinterpret_cast<const f16x8*>(vbase + (c + 2) * 64);
                bv1[cur] = *reinterpret_cast<const f16x8*>(vbase + (c + 2) * 64 + 32);
            }
            f16x8 a0 = *reinterpret_cast<const f16x8*>(scrow + c * 64 + quad * 8);
            f16x8 a1 = *reinterpret_cast<const f16x8*>(scrow + c * 64 + 32 + quad * 8);
            oacc = MFMA16(a0, cb0, oacc);
            oacc = MFMA16(a1, cb1, oacc);
        }
        if (khalf == 1) {
            #pragma unroll
            for (int r = 0; r < 4; ++r)
                red[dblk][quad * 4 + r][n16] = oacc[r];
        }
        __syncthreads();
        if (khalf == 0) {
            #pragma unroll
            for (int r = 0; r < 4; ++r) {
                int row = quad * 4 + r;
                float o = oacc[r] + red[dblk][row][n16];
                attno[(size_t)(row0 + row) * DK + dblk * 16 + n16] = o * st_il[row];
            }
        }
    }
}

// ===================== launch =====================
extern "C" void kernel_launch(void* const* d_in, const int* in_sizes, int n_in,
                              void* d_out, int out_size, void* d_ws, size_t ws_size,
                              hipStream_t stream) {
    const float* query = (const float*)d_in[0];
    const float* key   = (const float*)d_in[1];
    const float* value = (const float*)d_in[2];
    const int*   amask = (const int*)d_in[3];
    const float* Wq = (const float*)d_in[4];
    const float* bq = (const float*)d_in[5];
    const float* Wk = (const float*)d_in[6];
    const float* bk = (const float*)d_in[7];
    const float* Wv = (const float*)d_in[8];
    const float* bv = (const float*)d_in[9];

    float* attno = (float*)d_out;                      // [16384][64]
    float* aw    = attno + (size_t)NROW * DK;          // [8][2048][2048]

    char* ws = (char*)d_ws;
    _Float16* q16  = (_Float16*)(ws);                  // 2 MB
    _Float16* k16  = (_Float16*)(ws + (size_t)2097152);// 2 MB
    _Float16* vT16 = (_Float16*)(ws + (size_t)4194304);// 2 MB
    _Float16* w16  = (_Float16*)(ws + (size_t)6291456);// 192 KB

    wcvt<<<96, 256, 0, stream>>>(Wq, Wk, Wv, w16);
    proj<<<dim3(NROW / 64, 3), 256, 0, stream>>>(query, key, value, w16,
                                                 bq, bk, bv, q16, k16, vT16);
    attn<<<NROW / RT, 512, 0, stream>>>(q16, k16, vT16, amask, attno, aw);
}